// Round 1
// baseline (1212.225 us; speedup 1.0000x reference)
//
#include <hip/hip_runtime.h>

// 3-layer tanh RNN, fused per-layer (input-projection + recurrence in one
// kernel), fp32 VALU. One wave per batch row; lane j owns hidden element j.
// Weight rows in VGPRs (statically indexed, fully unrolled); input vectors
// multicast via LDS broadcast float4 reads. Layer 2 fuses the FC head.

#define RNN_B 1024
#define RNN_T 512
#define RNN_H 64
#define WPB   4   // waves (batch rows) per block -> 256 threads

__global__ __launch_bounds__(256, 1)
void rnn_layer_fused(const float* __restrict__ in,    // [B,T,H] layer input
                     float*       __restrict__ out,   // [B,T,H] layer output (null if last)
                     const float* __restrict__ Wih,   // [H,H] (row h, col i)
                     const float* __restrict__ Whh,   // [H,H]
                     const float* __restrict__ bih,   // [H]
                     const float* __restrict__ bhh,   // [H]
                     const float* __restrict__ fcw,   // [H]   (last layer only)
                     const float* __restrict__ fcb,   // [1]   (last layer only)
                     float*       __restrict__ fcout, // [B]   (last layer only)
                     int is_last)
{
    // Per-wave LDS: [wave][0]=x broadcast buf, [wave][1]=h broadcast buf
    __shared__ float4 lds[WPB][2][RNN_H / 4];

    const int lane = threadIdx.x & 63;
    const int wid  = threadIdx.x >> 6;
    const int b    = blockIdx.x * WPB + wid;

    // ---- Load weight rows: lane j holds Wih[j][0..63] and Whh[j][0..63] ----
    float wih[RNN_H], whh[RNN_H];
    {
        const float4* wr = (const float4*)(Wih + (size_t)lane * RNN_H);
        const float4* hr = (const float4*)(Whh + (size_t)lane * RNN_H);
#pragma unroll
        for (int c = 0; c < RNN_H / 4; ++c) {
            float4 a = wr[c];
            wih[4*c+0] = a.x; wih[4*c+1] = a.y; wih[4*c+2] = a.z; wih[4*c+3] = a.w;
            float4 d = hr[c];
            whh[4*c+0] = d.x; whh[4*c+1] = d.y; whh[4*c+2] = d.z; whh[4*c+3] = d.w;
        }
    }
    const float bias = bih[lane] + bhh[lane];

    float* xl = (float*)&lds[wid][0][0];
    float* hl = (float*)&lds[wid][1][0];
    hl[lane] = 0.0f;                         // h_0 = 0

    const float* inrow  = in + (size_t)b * RNN_T * RNN_H;
    float*       outrow = is_last ? nullptr : out + (size_t)b * RNN_T * RNN_H;

    float xreg = inrow[lane];                // x[b][0][lane]
    float hval = 0.0f;

    for (int t = 0; t < RNN_T; ++t) {
        // Publish x_t for broadcast; prefetch x_{t+1} (discarded at t=T-1).
        xl[lane] = xreg;
        const int tn = (t + 1 < RNN_T) ? (t + 1) : t;
        const float xnext = inrow[(size_t)tn * RNN_H + lane];

        float a0 = bias, a1 = 0.0f, a2 = 0.0f, a3 = 0.0f;

        // Input-projection part: out[j] += sum_i x[i] * Wih[j][i]
#pragma unroll
        for (int c = 0; c < RNN_H / 4; ++c) {
            float4 v = lds[wid][0][c];       // broadcast (same addr all lanes)
            a0 += v.x * wih[4*c+0];
            a1 += v.y * wih[4*c+1];
            a2 += v.z * wih[4*c+2];
            a3 += v.w * wih[4*c+3];
        }
        // Recurrent part: out[j] += sum_i h[i] * Whh[j][i]
#pragma unroll
        for (int c = 0; c < RNN_H / 4; ++c) {
            float4 v = lds[wid][1][c];       // broadcast
            a0 += v.x * whh[4*c+0];
            a1 += v.y * whh[4*c+1];
            a2 += v.z * whh[4*c+2];
            a3 += v.w * whh[4*c+3];
        }
        const float pre = (a0 + a1) + (a2 + a3);

        // tanh, overflow-safe: t = exp(-2|x|); r = (1-t)/(1+t); h = copysign(r,x)
        const float ax = fabsf(pre);
        const float e  = __expf(-2.0f * ax);
        const float r  = (1.0f - e) / (1.0f + e);
        hval = copysignf(r, pre);

        hl[lane] = hval;                     // publish h_t for next step
        if (!is_last) outrow[(size_t)t * RNN_H + lane] = hval;
        xreg = xnext;
    }

    if (is_last) {
        // FC head on last timestep: out[b] = sum_j h[j]*fcw[j] + fcb
        float p = hval * fcw[lane];
#pragma unroll
        for (int off = 32; off > 0; off >>= 1)
            p += __shfl_xor(p, off, 64);
        if (lane == 0) fcout[b] = p + fcb[0];
    }
}

extern "C" void kernel_launch(void* const* d_in, const int* in_sizes, int n_in,
                              void* d_out, int out_size, void* d_ws, size_t ws_size,
                              hipStream_t stream)
{
    const float* x   = (const float*)d_in[0];
    const float* Wih = (const float*)d_in[1];  // [3,H,H]
    const float* Whh = (const float*)d_in[2];  // [3,H,H]
    const float* bih = (const float*)d_in[3];  // [3,H]
    const float* bhh = (const float*)d_in[4];  // [3,H]
    const float* fcw = (const float*)d_in[5];  // [1,H]
    const float* fcb = (const float*)d_in[6];  // [1]
    float* out  = (float*)d_out;               // [B,1]
    float* hseq = (float*)d_ws;                // [B,T,H] fp32 = 128 MB scratch

    dim3 grid(RNN_B / WPB);
    dim3 block(WPB * 64);

    // Layer 0: x -> hseq
    rnn_layer_fused<<<grid, block, 0, stream>>>(
        x, hseq, Wih, Whh, bih, bhh, nullptr, nullptr, nullptr, 0);
    // Layer 1: hseq -> hseq (in-place safe: per-row reads of t+1 precede writes of t)
    rnn_layer_fused<<<grid, block, 0, stream>>>(
        hseq, hseq, Wih + RNN_H * RNN_H, Whh + RNN_H * RNN_H,
        bih + RNN_H, bhh + RNN_H, nullptr, nullptr, nullptr, 0);
    // Layer 2: hseq -> FC -> out  (no h-seq write)
    rnn_layer_fused<<<grid, block, 0, stream>>>(
        hseq, nullptr, Wih + 2 * RNN_H * RNN_H, Whh + 2 * RNN_H * RNN_H,
        bih + 2 * RNN_H, bhh + 2 * RNN_H, fcw, fcb, out, 1);
}

// Round 2
// 826.208 us; speedup vs baseline: 1.4672x; 1.4672x over previous
//
#include <hip/hip_runtime.h>

// 3-layer tanh RNN, fused per-layer. One wave per batch row; lane j owns
// hidden element j. Round-2 changes vs round-1:
//  - Weight rows PINNED in VGPRs via asm fence (round-1 VGPR_Count=84 proved
//    the compiler was re-loading weights from memory inside the T-loop).
//  - Dot products on ext_vector_type(2) floats -> v_pk_fma_f32 (2 FMA/instr).
//  - x_t and h_{t-1} published to LDS at end of previous iteration, so the
//    broadcast reads at the top of each step have no fresh-write dependence
//    except the unavoidable h ds_write->ds_read chain.

typedef __attribute__((ext_vector_type(2))) float f32x2;
typedef __attribute__((ext_vector_type(4))) float f32x4;

#define RNN_B 1024
#define RNN_T 512
#define RNN_H 64
#define WPB   4   // waves (batch rows) per block -> 256 threads

static __device__ __forceinline__ f32x2 mk2(float a, float b) {
    f32x2 r; r.x = a; r.y = b; return r;
}

__global__ __launch_bounds__(256, 1)
void rnn_layer_fused(const float* __restrict__ in,    // [B,T,H] layer input
                     float*       __restrict__ out,   // [B,T,H] layer output (null if last)
                     const float* __restrict__ Wih,   // [H,H] (row h, col i)
                     const float* __restrict__ Whh,   // [H,H]
                     const float* __restrict__ bih,   // [H]
                     const float* __restrict__ bhh,   // [H]
                     const float* __restrict__ fcw,   // [H]   (last layer only)
                     const float* __restrict__ fcb,   // [1]   (last layer only)
                     float*       __restrict__ fcout, // [B]   (last layer only)
                     int is_last)
{
    // Per-wave LDS: [wave][0]=x broadcast buf, [wave][1]=h broadcast buf
    __shared__ f32x4 lds[WPB][2][RNN_H / 4];

    const int lane = threadIdx.x & 63;
    const int wid  = threadIdx.x >> 6;
    const int b    = blockIdx.x * WPB + wid;

    // ---- Load weight rows: lane j holds Wih[j][*] and Whh[j][*] as f32x2 ----
    f32x2 wih2[RNN_H / 2], whh2[RNN_H / 2];
    {
        const f32x4* wr = (const f32x4*)(Wih + (size_t)lane * RNN_H);
        const f32x4* hr = (const f32x4*)(Whh + (size_t)lane * RNN_H);
#pragma unroll
        for (int c = 0; c < RNN_H / 4; ++c) {
            f32x4 a = wr[c];
            wih2[2*c+0] = mk2(a.x, a.y);
            wih2[2*c+1] = mk2(a.z, a.w);
            f32x4 d = hr[c];
            whh2[2*c+0] = mk2(d.x, d.y);
            whh2[2*c+1] = mk2(d.z, d.w);
        }
    }
    // Pin in VGPRs: value becomes opaque -> compiler cannot sink the weight
    // loads back into the T-loop (the round-1 failure mode).
#pragma unroll
    for (int i = 0; i < RNN_H / 2; ++i)
        asm volatile("" : "+v"(wih2[i]), "+v"(whh2[i]));

    const float bias = bih[lane] + bhh[lane];

    float* xl = (float*)&lds[wid][0][0];
    float* hl = (float*)&lds[wid][1][0];

    const float* inrow  = in + (size_t)b * RNN_T * RNN_H;
    float*       outrow = is_last ? nullptr : out + (size_t)b * RNN_T * RNN_H;

    // Prologue: publish x_0 and h_0 = 0; prefetch x_1 into xreg.
    xl[lane] = inrow[lane];
    hl[lane] = 0.0f;
    float xreg = inrow[RNN_H + lane];
    float hval = 0.0f;

    for (int t = 0; t < RNN_T; ++t) {
        // Broadcast fragments of x_t and h_{t-1} (published last iteration).
        f32x4 xv[RNN_H / 4], hv[RNN_H / 4];
#pragma unroll
        for (int c = 0; c < RNN_H / 4; ++c) xv[c] = lds[wid][0][c];
#pragma unroll
        for (int c = 0; c < RNN_H / 4; ++c) hv[c] = lds[wid][1][c];

        // 64 v_pk_fma_f32 per step (4 independent chains of 16).
        f32x2 a0 = mk2(0.f, 0.f), a1 = mk2(0.f, 0.f);
        f32x2 a2 = mk2(0.f, 0.f), a3 = mk2(0.f, 0.f);
#pragma unroll
        for (int c = 0; c < RNN_H / 4; ++c) {
            a0 += mk2(xv[c].x, xv[c].y) * wih2[2*c+0];
            a1 += mk2(xv[c].z, xv[c].w) * wih2[2*c+1];
            a2 += mk2(hv[c].x, hv[c].y) * whh2[2*c+0];
            a3 += mk2(hv[c].z, hv[c].w) * whh2[2*c+1];
        }
        const f32x2 s = (a0 + a1) + (a2 + a3);
        const float pre = (s.x + s.y) + bias;

        // tanh, overflow-safe: e = exp(-2|x|); r = (1-e)/(1+e); h = copysign(r,x)
        const float ax = fabsf(pre);
        const float e  = __expf(-2.0f * ax);
        const float r  = (1.0f - e) / (1.0f + e);
        hval = copysignf(r, pre);

        // Publish h_t; publish x_{t+1}; prefetch x_{t+2}.
        hl[lane] = hval;
        if (t + 1 < RNN_T) {
            xl[lane] = xreg;
            const int tn = (t + 2 < RNN_T) ? (t + 2) : (t + 1);
            xreg = inrow[(size_t)tn * RNN_H + lane];
        }
        if (!is_last) outrow[(size_t)t * RNN_H + lane] = hval;
    }

    if (is_last) {
        // FC head on last timestep: out[b] = sum_j h[j]*fcw[j] + fcb
        float p = hval * fcw[lane];
#pragma unroll
        for (int off = 32; off > 0; off >>= 1)
            p += __shfl_xor(p, off, 64);
        if (lane == 0) fcout[b] = p + fcb[0];
    }
}

extern "C" void kernel_launch(void* const* d_in, const int* in_sizes, int n_in,
                              void* d_out, int out_size, void* d_ws, size_t ws_size,
                              hipStream_t stream)
{
    const float* x   = (const float*)d_in[0];
    const float* Wih = (const float*)d_in[1];  // [3,H,H]
    const float* Whh = (const float*)d_in[2];  // [3,H,H]
    const float* bih = (const float*)d_in[3];  // [3,H]
    const float* bhh = (const float*)d_in[4];  // [3,H]
    const float* fcw = (const float*)d_in[5];  // [1,H]
    const float* fcb = (const float*)d_in[6];  // [1]
    float* out  = (float*)d_out;               // [B,1]
    float* hseq = (float*)d_ws;                // [B,T,H] fp32 = 128 MB scratch

    dim3 grid(RNN_B / WPB);
    dim3 block(WPB * 64);

    // Layer 0: x -> hseq
    rnn_layer_fused<<<grid, block, 0, stream>>>(
        x, hseq, Wih, Whh, bih, bhh, nullptr, nullptr, nullptr, 0);
    // Layer 1: hseq -> hseq (in-place safe: reads lead writes by >=1 step)
    rnn_layer_fused<<<grid, block, 0, stream>>>(
        hseq, hseq, Wih + RNN_H * RNN_H, Whh + RNN_H * RNN_H,
        bih + RNN_H, bhh + RNN_H, nullptr, nullptr, nullptr, 0);
    // Layer 2: hseq -> FC -> out  (no h-seq write)
    rnn_layer_fused<<<grid, block, 0, stream>>>(
        hseq, nullptr, Wih + 2 * RNN_H * RNN_H, Whh + 2 * RNN_H * RNN_H,
        bih + 2 * RNN_H, bhh + 2 * RNN_H, fcw, fcb, out, 1);
}